// Round 5
// baseline (4141.370 us; speedup 1.0000x reference)
//
#include <hip/hip_runtime.h>
#include <hip/hip_bf16.h>
#include <math.h>

namespace {

using bf16 = __hip_bfloat16;
typedef __bf16 bf16x8 __attribute__((ext_vector_type(8)));
typedef float f32x4 __attribute__((ext_vector_type(4)));

constexpr int N_ = 65536, E_ = 262144, G_ = 1024, M_ = 64;
constexpr int D_ = 512, H_ = 8, C_ = 64, ED_ = 128, P_ = 1024, L_ = 5;
constexpr float SLOPE = 0.2f;
constexpr float EPSF = 1.1920929e-7f;   // finfo(float32).eps

constexpr int NCH = 2;                  // FFN row chunks (hid aliases xlr)
constexpr int NCHUNK = N_ / NCH;        // 32768 rows/chunk

constexpr int TV = 22;                  // edge vocab per slot
constexpr int TK = TV * TV * TV;        // 10648 distinct edge types
constexpr int TKP = 10752;              // padded to %128

constexpr int CH = 4;                   // edges per online-softmax chunk

__device__ inline float b2f(bf16 h) { return __bfloat162float(h); }
__device__ inline bf16 f2b(float f) { return __float2bfloat16(f); }
__device__ inline float us2f(unsigned short u) {
  return __uint_as_float((unsigned)u << 16);
}
__device__ inline unsigned short f2us(float f) {
  bf16 b = __float2bfloat16(f);
  return *(unsigned short*)&b;
}

// fast erf-based exact GELU: A&S 7.1.26, |err| < 1.5e-7 (<< bf16 ulp)
__device__ inline float fast_gelu(float c) {
  float z = c * 0.70710678118654752f;
  float az = fabsf(z);
  float t = __builtin_amdgcn_rcpf(1.f + 0.3275911f * az);
  float e = __expf(-az * az);
  float poly =
      t * (0.254829592f +
           t * (-0.284496736f +
                t * (1.421413741f + t * (-1.453152027f + t * 1.061405429f))));
  float r = 1.f - poly * e;
  float erfv = (z < 0.f) ? -r : r;
  return 0.5f * c * (1.f + erfv);
}

// ---- async global->LDS, 16B/lane ----
typedef __attribute__((address_space(1))) void as1_void_t;
typedef __attribute__((address_space(3))) void as3_void_t;
__device__ inline void gload16(const void* g, void* l) {
  __builtin_amdgcn_global_load_lds((const as1_void_t*)g, (as3_void_t*)l, 16, 0,
                                   0);
}

// ============== MFMA bf16 GEMM: C[M,Nc] = A[M,K] @ Bt[Nc,K]^T + bias =========
// A row-major bf16, Bt = B^T row-major bf16. 128x128 tile, 4 waves (2x2),
// BK=64. 2-phase double-buffered staging (T3 minimum recipe): STAGE(next),
// COMPUTE(cur), one __syncthreads per K-step (its implicit vmcnt(0)/lgkmcnt(0)
// drain is exactly the required wait). XOR-swizzled global SOURCE + swizzled
// LDS read keeps ds_read_b128 conflict-free (G21 both-sides rule).
template <int EPI, int OBF>  // EPI: 0 none, 1 fast-exact gelu; OBF: bf16 out?
__global__ __launch_bounds__(256) void mfma_gemm_k(
    const ushort* __restrict__ A, const ushort* __restrict__ Bt,
    const float* __restrict__ bias, void* __restrict__ Cv, int M, int K,
    int Nc) {
  __shared__ __align__(16) ushort As[2][128 * 64];  // 2 x 16 KB
  __shared__ __align__(16) ushort Bs[2][128 * 64];
  const int tid = threadIdx.x;
  const int wave = tid >> 6, lane = tid & 63;
  const int m0 = blockIdx.x * 128, n0 = blockIdx.y * 128;
  const int wr = wave >> 1, wc = wave & 1;  // 2x2 wave grid, 64x64 each
  const int srow = tid >> 3;
  const int skoff = (((tid & 7) ^ (srow & 7)) << 3);  // inverse-swizzled source
  const ushort* Ap = A + (size_t)(m0 + srow) * K + skoff;
  const ushort* Bp = Bt + (size_t)(n0 + srow) * K + skoff;
  const int fr = lane & 15, fg = lane >> 4;
  const int rx = fr & 7;
  const int sA0 = ((fg) ^ rx) << 3;        // ks=0 slot offset (ushorts)
  const int sA1 = ((4 | fg) ^ rx) << 3;    // ks=1
  f32x4 acc[4][4];
#pragma unroll
  for (int i = 0; i < 4; ++i)
#pragma unroll
    for (int j = 0; j < 4; ++j) acc[i][j] = (f32x4){0.f, 0.f, 0.f, 0.f};

  auto STAGE = [&](int buf, int kt) {
#pragma unroll
    for (int r = 0; r < 4; ++r) {
      gload16(Ap + kt + (size_t)r * 32 * K,
              (char*)As[buf] + wave * 1024 + r * 4096);
      gload16(Bp + kt + (size_t)r * 32 * K,
              (char*)Bs[buf] + wave * 1024 + r * 4096);
    }
  };
  auto COMPUTE = [&](int buf) {
    const ushort* Arow = As[buf] + (wr * 64 + fr) * 64;
    const ushort* Brow = Bs[buf] + (wc * 64 + fr) * 64;
    bf16x8 af[4], bg[4];
#pragma unroll
    for (int i = 0; i < 4; ++i) af[i] = *(const bf16x8*)(Arow + i * 1024 + sA0);
#pragma unroll
    for (int j = 0; j < 4; ++j) bg[j] = *(const bf16x8*)(Brow + j * 1024 + sA0);
#pragma unroll
    for (int i = 0; i < 4; ++i)
#pragma unroll
      for (int j = 0; j < 4; ++j)
        acc[i][j] = __builtin_amdgcn_mfma_f32_16x16x32_bf16(af[i], bg[j],
                                                            acc[i][j], 0, 0, 0);
#pragma unroll
    for (int i = 0; i < 4; ++i) af[i] = *(const bf16x8*)(Arow + i * 1024 + sA1);
#pragma unroll
    for (int j = 0; j < 4; ++j) bg[j] = *(const bf16x8*)(Brow + j * 1024 + sA1);
#pragma unroll
    for (int i = 0; i < 4; ++i)
#pragma unroll
      for (int j = 0; j < 4; ++j)
        acc[i][j] = __builtin_amdgcn_mfma_f32_16x16x32_bf16(af[i], bg[j],
                                                            acc[i][j], 0, 0, 0);
  };

  STAGE(0, 0);
  __syncthreads();  // drain prologue stage
  int cur = 0;
  for (int kt = 64; kt < K; kt += 64) {
    STAGE(cur ^ 1, kt);   // issue next tile's loads (in flight over compute)
    COMPUTE(cur);
    __syncthreads();      // drains stage vmcnt + readers done with cur
    cur ^= 1;
  }
  COMPUTE(cur);  // last tile, nothing left to stage

  // epilogue: C/D frag mapping col=lane&15, row=(lane>>4)*4+reg (m89-verified)
  const int cb = n0 + wc * 64 + fr;
  float bv[4];
#pragma unroll
  for (int j = 0; j < 4; ++j) bv[j] = bias ? bias[cb + j * 16] : 0.f;
#pragma unroll
  for (int i = 0; i < 4; ++i) {
#pragma unroll
    for (int r = 0; r < 4; ++r) {
      int m = m0 + wr * 64 + i * 16 + fg * 4 + r;
      size_t rb = (size_t)m * Nc + cb;
#pragma unroll
      for (int j = 0; j < 4; ++j) {
        float c = acc[i][j][r] + bv[j];
        if (EPI == 1) c = fast_gelu(c);
        if (OBF)
          ((bf16*)Cv)[rb + j * 16] = f2b(c);
        else
          ((float*)Cv)[rb + j * 16] = c;
      }
    }
  }
}

// ---- 32x32 transpose+cvt tile helper (W[K][N] fp32 -> Wt[N][K] bf16) ----
__device__ inline void tr_tile(const float* __restrict__ W,
                               bf16* __restrict__ Wt, int K, int N,
                               int tileIdx, float* tile /*[32*33]*/) {
  int tilesN = N >> 5;
  int bn = (tileIdx % tilesN) << 5, bk = (tileIdx / tilesN) << 5;
  int tx = threadIdx.x & 31, ty = threadIdx.x >> 5;  // 32 x 8
#pragma unroll
  for (int i = ty; i < 32; i += 8)
    tile[i * 33 + tx] = W[(size_t)(bk + i) * N + bn + tx];
  __syncthreads();
#pragma unroll
  for (int i = ty; i < 32; i += 8)
    Wt[(size_t)(bn + i) * K + bk + tx] = f2b(tile[tx * 33 + i]);
}

// ---- one launch per layer: all 5 weight transposes + bias concat ----
__global__ __launch_bounds__(256) void prep_weights_k(
    const float* __restrict__ Wl, const float* __restrict__ Wr,
    const float* __restrict__ We, const float* __restrict__ f1w,
    const float* __restrict__ f2w, const float* __restrict__ bl,
    const float* __restrict__ br, bf16* __restrict__ Wlr_b,
    bf16* __restrict__ We_b, bf16* __restrict__ f1w_b,
    bf16* __restrict__ f2w_b, float* __restrict__ blr) {
  __shared__ float tile[32 * 33];
  int bid = blockIdx.x;
  if (bid < 256) {
    tr_tile(Wl, Wlr_b, 512, 512, bid, tile);
  } else if (bid < 512) {
    tr_tile(Wr, Wlr_b + 512 * 512, 512, 512, bid - 256, tile);
  } else if (bid < 576) {
    tr_tile(We, We_b, 128, 512, bid - 512, tile);
  } else if (bid < 1600) {
    tr_tile(f1w, f1w_b, 512, 2048, bid - 576, tile);
  } else if (bid < 2624) {
    tr_tile(f2w, f2w_b, 2048, 512, bid - 1600, tile);
  } else {
    int t = threadIdx.x;
#pragma unroll
    for (int k = 0; k < 4; ++k) {
      int i = t + k * 256;
      blr[i] = (i < 512) ? bl[i] : br[i - 512];
    }
  }
}

// ---- standalone transpose (head gapW) ----
__global__ __launch_bounds__(256) void transpose_cvt_k(
    const float* __restrict__ W, bf16* __restrict__ Wt, int K, int N) {
  __shared__ float tile[32 * 33];
  int tilesN = N >> 5;
  tr_tile(W, Wt, K, N, blockIdx.x + blockIdx.y * tilesN * 0, tile);
  (void)tilesN;
}

// ========== legacy fp32 SIMT GEMM (kept only for the tiny fp32 head) =========
template <int EPI, typename TIN, typename TOUT>
__global__ __launch_bounds__(256) void gemm_bias_k(
    const TIN* __restrict__ A, const float* __restrict__ B,
    const float* __restrict__ bias, TOUT* __restrict__ C, int M, int K,
    int Nc) {
  __shared__ float As[64][17];
  __shared__ float Bs[16][68];
  const int tid = threadIdx.x;
  const int m0 = blockIdx.x * 64;
  const int n0 = blockIdx.y * 64;
  const int ty = tid >> 4, tx = tid & 15;
  const int lam = tid >> 2;
  const int lak = (tid & 3) << 2;
  const int lbk = tid >> 4;
  const int lbn = (tid & 15) << 2;
  const TIN* Aptr = A + (long)(m0 + lam) * K + lak;
  const float* Bptr = B + (long)lbk * Nc + n0 + lbn;
  float acc[4][4] = {};
  for (int kt = 0; kt < K; kt += 16) {
    float4 va = *(const float4*)(Aptr + kt);
    float4 vb = *(const float4*)(Bptr + (long)kt * Nc);
    __syncthreads();
    As[lam][lak + 0] = va.x; As[lam][lak + 1] = va.y;
    As[lam][lak + 2] = va.z; As[lam][lak + 3] = va.w;
    Bs[lbk][lbn + 0] = vb.x; Bs[lbk][lbn + 1] = vb.y;
    Bs[lbk][lbn + 2] = vb.z; Bs[lbk][lbn + 3] = vb.w;
    __syncthreads();
#pragma unroll
    for (int kk = 0; kk < 16; ++kk) {
      float a[4], b[4];
#pragma unroll
      for (int i = 0; i < 4; ++i) a[i] = As[ty * 4 + i][kk];
#pragma unroll
      for (int j = 0; j < 4; ++j) b[j] = Bs[kk][tx * 4 + j];
#pragma unroll
      for (int i = 0; i < 4; ++i)
#pragma unroll
        for (int j = 0; j < 4; ++j) acc[i][j] = fmaf(a[i], b[j], acc[i][j]);
    }
  }
#pragma unroll
  for (int i = 0; i < 4; ++i) {
    long row = (long)(m0 + ty * 4 + i) * Nc + n0;
#pragma unroll
    for (int j = 0; j < 4; ++j) {
      float c = acc[i][j] + (bias ? bias[n0 + tx * 4 + j] : 0.f);
      if (EPI == 1) c = fast_gelu(c);
      ((float*)C)[row + tx * 4 + j] = c;
    }
  }
}

// ================= encoders =================
__global__ __launch_bounds__(256) void encode_nodes_k(
    const int* __restrict__ nodeX, const float* __restrict__ atomEmb,
    bf16* __restrict__ x) {
  int n = blockIdx.x, tid = threadIdx.x;
  __shared__ int idx[9];
  if (tid < 9) idx[tid] = nodeX[n * 9 + tid];
  __syncthreads();
  for (int d = tid; d < D_; d += 256) {
    float s = 0.f;
#pragma unroll
    for (int k = 0; k < 9; ++k) s += atomEmb[(k * 119 + idx[k]) * D_ + d];
    x[(long)n * D_ + d] = f2b(s);
  }
}

// edge-type key per edge: key = i0*TV^2 + i1*TV + i2  (layer-invariant)
__global__ __launch_bounds__(256) void build_keys_k(
    const int* __restrict__ eai, int* __restrict__ keys) {
  int e = blockIdx.x * 256 + threadIdx.x;
  keys[e] = eai[e * 3] * (TV * TV) + eai[e * 3 + 1] * TV + eai[e * 3 + 2];
}

// eattr table: one row per distinct (i0,i1,i2); rows >= TK zeroed (GEMM pad)
__global__ __launch_bounds__(128) void build_eattr_tab_k(
    const float* __restrict__ edgeEmb, bf16* __restrict__ tab) {
  int r = blockIdx.x, d = threadIdx.x;
  float s = 0.f;
  if (r < TK) {
    int k0 = r / (TV * TV), k1 = (r / TV) % TV, k2 = r % TV;
    s = edgeEmb[(0 * TV + k0) * ED_ + d] + edgeEmb[(1 * TV + k1) * ED_ + d] +
        edgeEmb[(2 * TV + k2) * ED_ + d];
  }
  tab[(size_t)r * ED_ + d] = f2b(s);
}

// ===== fully-fused GATv2 layer: logits + segment-softmax + aggregate + gb +
// ===== residual + rmsnorm. ONE WAVE PER NODE, no LDS, no block barriers.
// xlr[n][0..511] = xl row, xlr[n][512..1023] = xr row (fused projection).
__global__ __launch_bounds__(256) void gat_fused_k(
    bf16* __restrict__ x, const ushort* __restrict__ xlr,
    const ushort* __restrict__ ee_tab, const int* __restrict__ keys,
    const float* __restrict__ att, const int* __restrict__ ptr,
    const int* __restrict__ eid, const int* __restrict__ src,
    const float* __restrict__ gb, const float* __restrict__ w) {
  const int wave = threadIdx.x >> 6, lane = threadIdx.x & 63;
  const int n = blockIdx.x * 4 + wave;
  const int d0 = lane * 8;
  const int beg = ptr[n], deg = ptr[n + 1] - beg;

  // per-lane att slice (same head for all 8 elems)
  float4 a0 = *(const float4*)(att + d0);
  float4 a1 = *(const float4*)(att + d0 + 4);
  float attv[8] = {a0.x, a0.y, a0.z, a0.w, a1.x, a1.y, a1.z, a1.w};
  // xr[n] row, kept in registers
  uint4 xru = *(const uint4*)(xlr + (size_t)n * 1024 + 512 + d0);
  float xrf[8];
#pragma unroll
  for (int q = 0; q < 4; ++q) {
    unsigned u = (&xru.x)[q];
    xrf[2 * q] = us2f((ushort)u);
    xrf[2 * q + 1] = us2f((ushort)(u >> 16));
  }

  float m = -__builtin_inff(), den = 0.f;
  float acc[8] = {0.f, 0.f, 0.f, 0.f, 0.f, 0.f, 0.f, 0.f};

  for (int c0 = 0; c0 < deg; c0 += CH) {
    int cn = min(deg - c0, CH);
    int s_l = 0, k_l = 0;
    if (lane < cn) {
      int e = eid[beg + c0 + lane];
      s_l = src[e];
      k_l = keys[e];
    }
    uint4 xlv[CH];
    float lg[CH];
#pragma unroll
    for (int i = 0; i < CH; ++i) {
      lg[i] = -__builtin_inff();
      if (i < cn) {
        int s = __shfl(s_l, i);
        int k = __shfl(k_l, i);
        xlv[i] = *(const uint4*)(xlr + (size_t)s * 1024 + d0);
        uint4 ev = *(const uint4*)(ee_tab + (size_t)k * D_ + d0);
        float part = 0.f;
#pragma unroll
        for (int q = 0; q < 4; ++q) {
          unsigned ua = (&xlv[i].x)[q];
          unsigned ue = (&ev.x)[q];
          float v0 = us2f((ushort)ua) + xrf[2 * q] + us2f((ushort)ue);
          float v1 =
              us2f((ushort)(ua >> 16)) + xrf[2 * q + 1] + us2f((ushort)(ue >> 16));
          v0 = (v0 > 0.f) ? v0 : SLOPE * v0;
          v1 = (v1 > 0.f) ? v1 : SLOPE * v1;
          part = fmaf(v0, attv[2 * q], part);
          part = fmaf(v1, attv[2 * q + 1], part);
        }
        // reduce over the 8-lane head group (lanes l^1, l^2, l^4 same head)
        part += __shfl_xor(part, 1);
        part += __shfl_xor(part, 2);
        part += __shfl_xor(part, 4);
        lg[i] = part;
      }
    }
    // online softmax: rescale running state to the new max
    float cm = lg[0];
#pragma unroll
    for (int i = 1; i < CH; ++i) cm = fmaxf(cm, lg[i]);
    if (cm > m) {
      float sc = expf(m - cm);  // first chunk: exp(-inf)=0 zeroes empty state
      den *= sc;
#pragma unroll
      for (int j = 0; j < 8; ++j) acc[j] *= sc;
      m = cm;
    }
#pragma unroll
    for (int i = 0; i < CH; ++i) {
      if (i < cn) {
        float p = expf(lg[i] - m);
        den += p;
#pragma unroll
        for (int q = 0; q < 4; ++q) {
          unsigned ua = (&xlv[i].x)[q];
          acc[2 * q] = fmaf(us2f((ushort)ua), p, acc[2 * q]);
          acc[2 * q + 1] = fmaf(us2f((ushort)(ua >> 16)), p, acc[2 * q + 1]);
        }
      }
    }
  }

  float inv = (deg > 0) ? 1.f / den : 0.f;
  uint4 xu = *(const uint4*)((const ushort*)x + (size_t)n * D_ + d0);
  float4 g0 = *(const float4*)(gb + d0);
  float4 g1 = *(const float4*)(gb + d0 + 4);
  float gbv[8] = {g0.x, g0.y, g0.z, g0.w, g1.x, g1.y, g1.z, g1.w};
  float v[8], ss = 0.f;
#pragma unroll
  for (int q = 0; q < 4; ++q) {
    unsigned u = (&xu.x)[q];
    v[2 * q] = us2f((ushort)u) + acc[2 * q] * inv + gbv[2 * q];
    v[2 * q + 1] = us2f((ushort)(u >> 16)) + acc[2 * q + 1] * inv + gbv[2 * q + 1];
  }
#pragma unroll
  for (int j = 0; j < 8; ++j) ss += v[j] * v[j];
#pragma unroll
  for (int o = 1; o < 64; o <<= 1) ss += __shfl_xor(ss, o);
  float scale = rsqrtf(ss * (1.0f / D_) + EPSF);
  float4 w0 = *(const float4*)(w + d0);
  float4 w1 = *(const float4*)(w + d0 + 4);
  float wv[8] = {w0.x, w0.y, w0.z, w0.w, w1.x, w1.y, w1.z, w1.w};
  uint4 outv;
#pragma unroll
  for (int q = 0; q < 4; ++q) {
    unsigned lo = f2us(v[2 * q] * scale * wv[2 * q]);
    unsigned hi = f2us(v[2 * q + 1] * scale * wv[2 * q + 1]);
    (&outv.x)[q] = lo | (hi << 16);
  }
  *(uint4*)((ushort*)x + (size_t)n * D_ + d0) = outv;
}

// ================= rmsnorm(x + xa) for the FFN residual =================
__global__ __launch_bounds__(256) void rmsnorm_res_k(
    bf16* __restrict__ x, const float* __restrict__ xa,
    const float* __restrict__ w) {
  int n = blockIdx.x, tid = threadIdx.x;
  long base = (long)n * D_;
  float v0 = b2f(x[base + tid]) + xa[base + tid];
  float v1 = b2f(x[base + tid + 256]) + xa[base + tid + 256];
  float ss = v0 * v0 + v1 * v1;
#pragma unroll
  for (int o = 32; o > 0; o >>= 1) ss += __shfl_xor(ss, o);
  __shared__ float wsum[4];
  if ((tid & 63) == 0) wsum[tid >> 6] = ss;
  __syncthreads();
  float tot = wsum[0] + wsum[1] + wsum[2] + wsum[3];
  float scale = rsqrtf(tot * (1.0f / D_) + EPSF);
  x[base + tid] = f2b(v0 * scale * w[tid]);
  x[base + tid + 256] = f2b(v1 * scale * w[tid + 256]);
}

// ================= bookkeeping =================
__global__ void zero_int_k(int* __restrict__ p) {
  p[blockIdx.x * 256 + threadIdx.x] = 0;
}
__global__ void count_k(const int* __restrict__ key, int* __restrict__ counts) {
  int id = blockIdx.x * 256 + threadIdx.x;
  atomicAdd(&counts[key[id]], 1);
}
__global__ void copy_int_k(const int* __restrict__ in, int* __restrict__ out) {
  int id = blockIdx.x * 256 + threadIdx.x;
  out[id] = in[id];
}
__global__ void fill_csr_k(const int* __restrict__ dst,
                           int* __restrict__ cursor, int* __restrict__ eid) {
  int e = blockIdx.x * 256 + threadIdx.x;
  int pos = atomicAdd(&cursor[dst[e]], 1);
  eid[pos] = e;
}
// exclusive scan over N=65536 ints, single block of 1024 threads
__global__ __launch_bounds__(1024) void scanN_k(const int* __restrict__ cnt,
                                                int* __restrict__ ptr) {
  __shared__ int sums[1024];
  int t = threadIdx.x;
  int base = t * 64;
  int s = 0;
  for (int i = 0; i < 64; ++i) s += cnt[base + i];
  sums[t] = s;
  __syncthreads();
  for (int off = 1; off < 1024; off <<= 1) {
    int v = (t >= off) ? sums[t - off] : 0;
    __syncthreads();
    sums[t] += v;
    __syncthreads();
  }
  int run = (t > 0) ? sums[t - 1] : 0;
  for (int i = 0; i < 64; ++i) {
    ptr[base + i] = run;
    run += cnt[base + i];
  }
  if (t == 1023) ptr[N_] = run;
}
__global__ void scan_k(const int* __restrict__ counts, int* __restrict__ starts) {
  __shared__ int buf[G_];
  int t = threadIdx.x;
  int c = counts[t];
  buf[t] = c;
  __syncthreads();
  for (int off = 1; off < G_; off <<= 1) {
    int v = (t >= off) ? buf[t - off] : 0;
    __syncthreads();
    buf[t] += v;
    __syncthreads();
  }
  starts[t] = buf[t] - c;  // exclusive
}

// ================= attention pooling (z is bf16) =================
__global__ __launch_bounds__(256) void pool_k(
    const bf16* __restrict__ z, const float* __restrict__ avW,
    const float* __restrict__ avb, const int* __restrict__ counts,
    const int* __restrict__ starts, float* __restrict__ hg) {
  int g = blockIdx.x, tid = threadIdx.x;
  int cnt = counts[g], st = starts[g];
  __shared__ float aL[M_];
  int wave = tid >> 6, lane = tid & 63;
  for (int m = wave; m < M_; m += 4) {
    float s = 0.f;
    if (m < cnt) {
      const bf16* row = z + (long)(st + m) * D_;
      for (int c = lane; c < D_; c += 64) s += b2f(row[c]) * avW[c];
    }
#pragma unroll
    for (int o = 32; o > 0; o >>= 1) s += __shfl_xor(s, o);
    if (lane == 0) aL[m] = s;
  }
  __syncthreads();
  if (tid < 64) {
    float v = (tid < cnt) ? aL[tid] + avb[0] : -__builtin_inff();
    float mxv = v;
#pragma unroll
    for (int o = 32; o > 0; o >>= 1) mxv = fmaxf(mxv, __shfl_xor(mxv, o));
    float p = (tid < cnt) ? expf(v - mxv) : 0.f;
    float sm = p;
#pragma unroll
    for (int o = 32; o > 0; o >>= 1) sm += __shfl_xor(sm, o);
    aL[tid] = p / sm;
  }
  __syncthreads();
  for (int d = tid; d < D_; d += 256) {
    float acc = 0.f;
    for (int m = 0; m < cnt; ++m) acc += b2f(z[(long)(st + m) * D_ + d]) * aL[m];
    hg[(long)g * D_ + d] = acc;
  }
}

__global__ __launch_bounds__(256) void rms_relu_k(
    const float* __restrict__ in, const float* __restrict__ w,
    float* __restrict__ out) {
  int g = blockIdx.x, tid = threadIdx.x;
  long base = (long)g * P_;
  float v[4], ss = 0.f;
#pragma unroll
  for (int k = 0; k < 4; ++k) {
    v[k] = in[base + tid + k * 256];
    ss += v[k] * v[k];
  }
#pragma unroll
  for (int o = 32; o > 0; o >>= 1) ss += __shfl_xor(ss, o);
  __shared__ float wsum[4];
  if ((tid & 63) == 0) wsum[tid >> 6] = ss;
  __syncthreads();
  float tot = wsum[0] + wsum[1] + wsum[2] + wsum[3];
  float scale = rsqrtf(tot * (1.0f / P_) + EPSF);
#pragma unroll
  for (int k = 0; k < 4; ++k) {
    float c = v[k] * scale * w[tid + k * 256];
    out[base + tid + k * 256] = fmaxf(c, 0.f);
  }
}

// ================= final outputs =================
__global__ __launch_bounds__(256) void write_dense_k(
    const bf16* __restrict__ x, const int* __restrict__ counts,
    const int* __restrict__ starts, float* __restrict__ out1) {
  long id = (long)blockIdx.x * 256 + threadIdx.x;  // G*M*D
  int g = (int)(id >> 15);
  int rem = (int)(id & 32767);
  int m = rem >> 9, d = rem & 511;
  float v = 0.f;
  if (m < counts[g]) v = b2f(x[(long)(starts[g] + m) * D_ + d]);
  out1[id] = v;
}
__global__ void write_mask_k(const int* __restrict__ counts,
                             float* __restrict__ out2) {
  int id = blockIdx.x * 256 + threadIdx.x;  // G*M
  out2[id] = ((id & 63) < counts[id >> 6]) ? 1.f : 0.f;
}

}  // namespace

extern "C" void kernel_launch(void* const* d_in, const int* in_sizes, int n_in,
                              void* d_out, int out_size, void* d_ws,
                              size_t ws_size, hipStream_t stream) {
  const int* node_x = (const int*)d_in[0];
  const int* edge_attr_idx = (const int*)d_in[1];
  const int* edge_index = (const int*)d_in[2];
  const int* batch = (const int*)d_in[3];
  const float* atom_emb = (const float*)d_in[4];
  const float* edge_emb = (const float*)d_in[5];
  const float* Wl = (const float*)d_in[6];
  const float* bl = (const float*)d_in[7];
  const float* Wr = (const float*)d_in[8];
  const float* br = (const float*)d_in[9];
  const float* We = (const float*)d_in[10];
  const float* att = (const float*)d_in[11];
  const float* gb = (const float*)d_in[12];
  const float* n1w = (const float*)d_in[13];
  const float* f1w = (const float*)d_in[14];
  const float* f1b = (const float*)d_in[15];
  const float* f2w = (const float*)d_in[16];
  const float* f2b = (const float*)d_in[17];
  const float* n2w = (const float*)d_in[18];
  const float* gapW = (const float*)d_in[19];
  const float* gapb = (const float*)d_in[20];
  const float* avW = (const float*)d_in[21];
  const float* avb = (const float*)d_in[22];
  const float* p1W = (const float*)d_in[23];
  const float* p1b = (const float*)d_in[24];
  const float* pnw = (const float*)d_in[25];
  const float* p2W = (const float*)d_in[26];
  const float* p2b = (const float*)d_in[27];
  const int* src = edge_index;
  const int* dst = edge_index + E_;

  // ---- workspace layout ----
  char* ws = (char*)d_ws;
  bf16* x = (bf16*)ws;                                   // N*D bf16
  bf16* xlr = x + (long)N_ * D_;                         // N*1024 bf16 (xl|xr)
  bf16* region = xlr + (long)N_ * 1024;  // 41.9MB region
  bf16* ee_tab = region;                                 // TKP*D bf16 = 11MB
  bf16* eattr_tab = ee_tab + (long)TKP * D_;             // TKP*ED bf16 = 2.75MB
  float* spare = (float*)(region + (long)32768 * D_ + (long)32768 * ED_);
  int* keys = (int*)(spare + (long)E_ * H_);             // E ints
  float* spare2 = (float*)(keys + N_ * H_);
  int* counts = (int*)(spare2 + (long)N_ * H_);          // G
  int* starts = counts + G_;                             // G
  float* hg = (float*)(starts + G_);                     // G*D fp32
  float* tmpP = hg + (long)G_ * D_;                      // G*P fp32
  float* hp = tmpP + (long)G_ * P_;                      // G*P fp32
  // FFN hidden buffer aliases xlr (dead during FFN phase):
  // NCHUNK*4D bf16 = 32768*2048*2 B = 134.2 MB = |xlr| exactly.
  bf16* hid = xlr;

  // per-layer bf16 transposed weights, aliased on tmpP+hp (dead during layers)
  bf16* wsc = (bf16*)tmpP;  // 8.39 MB available, 5.37 MB used
  bf16* Wlr_b = wsc;                      // [1024][512]  (Wl^T | Wr^T rows)
  bf16* We_b = Wlr_b + 1024 * 512;        // [512][128]
  bf16* f1w_b = We_b + 512 * 128;         // [2048][512]
  bf16* f2w_b = f1w_b + 2048 * 512;       // [512][2048]
  float* blr = (float*)(f2w_b + 512 * 2048);  // [1024] = bl|br

  float* out0 = (float*)d_out;                 // [G,P]
  float* out1 = out0 + (long)G_ * P_;          // [G,M,D]
  float* out2 = out1 + (long)G_ * M_ * D_;     // [G,M]
  float* xa = out1;  // FFN residual accumulator aliases out1 (dead at end)

  // dst-CSR lives in out0 (written only at the very end of the launch)
  int* csr_eid = (int*)out0;        // E
  int* csr_ptr = csr_eid + E_;      // N+1
  int* cursor = csr_ptr + N_ + 1;   // N

  encode_nodes_k<<<N_, 256, 0, stream>>>(node_x, atom_emb, x);

  // ---- one-time: edge-type keys + eattr table; dst-CSR ----
  build_keys_k<<<E_ / 256, 256, 0, stream>>>(edge_attr_idx, keys);
  build_eattr_tab_k<<<TKP, 128, 0, stream>>>(edge_emb, eattr_tab);
  zero_int_k<<<N_ / 256, 256, 0, stream>>>(cursor);
  count_k<<<E_ / 256, 256, 0, stream>>>(dst, cursor);
  scanN_k<<<1, 1024, 0, stream>>>(cursor, csr_ptr);
  copy_int_k<<<N_ / 256, 256, 0, stream>>>(csr_ptr, cursor);
  fill_csr_k<<<E_ / 256, 256, 0, stream>>>(dst, cursor, csr_eid);

  for (int l = 0; l < L_; ++l) {
    const float* Wl_l = Wl + (long)l * D_ * D_;
    const float* bl_l = bl + (long)l * D_;
    const float* Wr_l = Wr + (long)l * D_ * D_;
    const float* br_l = br + (long)l * D_;
    const float* We_l = We + (long)l * ED_ * D_;
    const float* att_l = att + (long)l * H_ * C_;
    const float* gb_l = gb + (long)l * D_;
    const float* n1w_l = n1w + (long)l * D_;
    const float* f1w_l = f1w + (long)l * D_ * 4 * D_;
    const float* f1b_l = f1b + (long)l * 4 * D_;
    const float* f2w_l = f2w + (long)l * 4 * D_ * D_;
    const float* f2b_l = f2b + (long)l * D_;
    const float* n2w_l = n2w + (long)l * D_;

    // all weight preps for this layer in one launch
    prep_weights_k<<<2625, 256, 0, stream>>>(Wl_l, Wr_l, We_l, f1w_l, f2w_l,
                                             bl_l, br_l, Wlr_b, We_b, f1w_b,
                                             f2w_b, blr);

    // fused xl|xr projection: [N, 1024] = x @ [Wl|Wr]
    mfma_gemm_k<0, 1><<<dim3(N_ / 128, 1024 / 128), 256, 0, stream>>>(
        (const ushort*)x, (const ushort*)Wlr_b, blr, xlr, N_, D_, 1024);
    // ee table for this layer: [TKP, D] = eattr_tab @ We
    mfma_gemm_k<0, 1><<<dim3(TKP / 128, D_ / 128), 256, 0, stream>>>(
        (const ushort*)eattr_tab, (const ushort*)We_b, nullptr, ee_tab, TKP,
        ED_, D_);

    gat_fused_k<<<N_ / 4, 256, 0, stream>>>(
        x, (const ushort*)xlr, (const ushort*)ee_tab, keys, att_l, csr_ptr,
        csr_eid, src, gb_l, n1w_l);

    for (int nc = 0; nc < NCH; ++nc) {
      long nbase = (long)nc * NCHUNK;
      mfma_gemm_k<1, 1><<<dim3(NCHUNK / 128, (4 * D_) / 128), 256, 0, stream>>>(
          (const ushort*)(x + nbase * D_), (const ushort*)f1w_b, f1b_l, hid,
          NCHUNK, D_, 4 * D_);
      mfma_gemm_k<0, 0><<<dim3(NCHUNK / 128, D_ / 128), 256, 0, stream>>>(
          (const ushort*)hid, (const ushort*)f2w_b, f2b_l, xa + nbase * D_,
          NCHUNK, 4 * D_, D_);
    }
    rmsnorm_res_k<<<N_, 256, 0, stream>>>(x, xa, n2w_l);
  }

  // batch bookkeeping
  zero_int_k<<<G_ / 256, 256, 0, stream>>>(counts);
  count_k<<<N_ / 256, 256, 0, stream>>>(batch, counts);
  scan_k<<<1, G_, 0, stream>>>(counts, starts);

  // pooling head: z into xlr (free now); gapW bf16^T into eattr_tab slot
  bf16* gapW_b = eattr_tab;
  transpose_cvt_k<<<256, 256, 0, stream>>>(gapW, gapW_b, 512, 512);
  bf16* z = xlr;
  mfma_gemm_k<0, 1><<<dim3(N_ / 128, D_ / 128), 256, 0, stream>>>(
      (const ushort*)x, (const ushort*)gapW_b, gapb, z, N_, D_, D_);
  pool_k<<<G_, 256, 0, stream>>>(z, avW, avb, counts, starts, hg);
  gemm_bias_k<0, float, float><<<dim3(G_ / 64, P_ / 64), 256, 0, stream>>>(
      hg, p1W, p1b, tmpP, G_, D_, P_);
  rms_relu_k<<<G_, 256, 0, stream>>>(tmpP, pnw, hp);
  gemm_bias_k<0, float, float><<<dim3(G_ / 64, P_ / 64), 256, 0, stream>>>(
      hp, p2W, p2b, out0, G_, P_, P_);

  write_dense_k<<<(int)(((long)G_ * M_ * D_) / 256), 256, 0, stream>>>(
      x, counts, starts, out1);
  write_mask_k<<<(G_ * M_) / 256, 256, 0, stream>>>(counts, out2);
}